// Round 4
// baseline (249.724 us; speedup 1.0000x reference)
//
#include <hip/hip_runtime.h>

#define S_LEN 2048
#define E_DIM 1024
#define NH 16
#define DHD 64
#define DMODEL 1024

typedef unsigned short u16;
typedef __attribute__((ext_vector_type(8))) short bf16x8;   // 8 bf16 = 4 VGPRs
typedef __attribute__((ext_vector_type(4))) float f32x4;

static constexpr float GN_EPS = 1e-5f;
// 1/sqrt(64) * log2(e): scores pre-scaled so softmax uses raw v_exp_f32 (2^x)
static constexpr float QSCALE_LOG2E = 0.125f * 1.44269504088896340736f;

struct alignas(8) U16x4 { u16 x, y, z, w; };

__device__ __forceinline__ u16 f2bf(float f) {            // RNE
    union { float f; unsigned u; } v; v.f = f;
    unsigned r = v.u + 0x7fffu + ((v.u >> 16) & 1u);
    return (u16)(r >> 16);
}
__device__ __forceinline__ u16 f2bf_trunc(float f) {      // truncate: free via d16_hi store
    union { float f; unsigned u; } v; v.f = f;
    return (u16)(v.u >> 16);
}
__device__ __forceinline__ float bf2f(u16 u) {
    union { unsigned u; float f; } v; v.u = ((unsigned)u) << 16; return v.f;
}

__device__ __forceinline__ f32x4 fzero() { f32x4 z = {0.f, 0.f, 0.f, 0.f}; return z; }

// ---------------------------------------------------------------------------
// async 16B/lane global->LDS. LDS dest = wave-uniform base + lane*16.
// ---------------------------------------------------------------------------
__device__ __forceinline__ void async16(const u16* g, u16* l) {
    __builtin_amdgcn_global_load_lds(
        (const __attribute__((address_space(1))) unsigned int*)g,
        (__attribute__((address_space(3))) unsigned int*)l, 16, 0, 0);
}

// Stage 8 rows (r0..r0+7, r0 % 8 == 0) of a 64-col bf16 tile into XOR-swizzled
// LDS. Logical (r,c) lives at byte r*128 + (((c>>3) ^ (r&7))*16) + (c&7)*2.
__device__ __forceinline__ void stage8(const u16* gbase, int gstride, u16* lds,
                                       int r0, int l) {
    const int cg = (l & 7) ^ (l >> 3);
    async16(gbase + (size_t)(r0 + (l >> 3)) * gstride + cg * 8, lds + r0 * 64);
}

__device__ __forceinline__ bf16x8 ldsfrag(const u16* lds, int r, int chunk) {
    return *(const bf16x8*)((const char*)lds + r * 128 + ((chunk ^ (r & 7)) << 4));
}

// ---------------------------------------------------------------------------
// fp32 -> bf16: x, 5 projection weights (into one concatenated [5120][1024]
// buffer), Wo. grid.z selects tensor.
// ---------------------------------------------------------------------------
__global__ __launch_bounds__(256) void f2b_kernel(
    const float* __restrict__ x,
    const float* __restrict__ w0, const float* __restrict__ w1,
    const float* __restrict__ w2, const float* __restrict__ w3,
    const float* __restrict__ w4, const float* __restrict__ wo,
    u16* __restrict__ xb, u16* __restrict__ wall, u16* __restrict__ dwo)
{
    const int z = blockIdx.z;
    const float* src; u16* dst; int n;
    const int nw = NH * DHD * E_DIM;
    switch (z) {
        case 0: src = x;  dst = xb;            n = S_LEN * E_DIM;  break;
        case 1: src = w0; dst = wall;          n = nw; break;
        case 2: src = w1; dst = wall + nw;     n = nw; break;
        case 3: src = w2; dst = wall + 2 * nw; n = nw; break;
        case 4: src = w3; dst = wall + 3 * nw; n = nw; break;
        case 5: src = w4; dst = wall + 4 * nw; n = nw; break;
        default: src = wo; dst = dwo;          n = DMODEL * E_DIM; break;
    }
    int i = blockIdx.x * 256 + threadIdx.x;
    if (i * 4 < n) {
        float4 v = ((const float4*)src)[i];
        U16x4 o;
        o.x = f2bf(v.x); o.y = f2bf(v.y); o.z = f2bf(v.z); o.w = f2bf(v.w);
        ((U16x4*)dst)[i] = o;
    }
}

// ---------------------------------------------------------------------------
// Fused projection GEMM: [2048 x 1024] x [5120 x 1024]^T, 128x128 tile.
// n -> {tensor t, head h, dim d}. q1/q2 pre-scaled by QSCALE_LOG2E;
// v written transposed vt[h][d][s].  grid (16, 40), 4 waves, 4x4 accs each.
// ---------------------------------------------------------------------------
__global__ __launch_bounds__(256) void proj_mfma_kernel(
    const u16* __restrict__ xb, const u16* __restrict__ wall,
    const float* __restrict__ bq1, const float* __restrict__ bq2,
    const float* __restrict__ bk1, const float* __restrict__ bk2,
    const float* __restrict__ bv,
    u16* __restrict__ qk, u16* __restrict__ vt)
{
    __shared__ u16 As[128 * 64], Bs[128 * 64];
    const int m0 = blockIdx.x * 128, n0 = blockIdx.y * 128;
    const int t = threadIdx.x, w = t >> 6, l = t & 63;
    const int lane15 = l & 15, quad = l >> 4;
    const int wr = (w >> 1) * 64, wc = (w & 1) * 64;

    f32x4 acc[4][4];
    #pragma unroll
    for (int mi = 0; mi < 4; ++mi)
        #pragma unroll
        for (int ni = 0; ni < 4; ++ni) acc[mi][ni] = fzero();

    const u16* Ag = xb + (size_t)m0 * E_DIM;
    const u16* Bg = wall + (size_t)n0 * E_DIM;

    for (int k0 = 0; k0 < E_DIM; k0 += 64) {
        __syncthreads();
        #pragma unroll
        for (int i = 0; i < 4; ++i) stage8(Ag + k0, E_DIM, As, w * 32 + i * 8, l);
        #pragma unroll
        for (int i = 0; i < 4; ++i) stage8(Bg + k0, E_DIM, Bs, w * 32 + i * 8, l);
        __syncthreads();

        bf16x8 a[4][2], b[4][2];
        #pragma unroll
        for (int mi = 0; mi < 4; ++mi) {
            a[mi][0] = ldsfrag(As, wr + mi * 16 + lane15, quad);
            a[mi][1] = ldsfrag(As, wr + mi * 16 + lane15, 4 + quad);
        }
        #pragma unroll
        for (int ni = 0; ni < 4; ++ni) {
            b[ni][0] = ldsfrag(Bs, wc + ni * 16 + lane15, quad);
            b[ni][1] = ldsfrag(Bs, wc + ni * 16 + lane15, 4 + quad);
        }
        #pragma unroll
        for (int mi = 0; mi < 4; ++mi)
            #pragma unroll
            for (int ni = 0; ni < 4; ++ni) {
                acc[mi][ni] = __builtin_amdgcn_mfma_f32_16x16x32_bf16(
                    a[mi][0], b[ni][0], acc[mi][ni], 0, 0, 0);
                acc[mi][ni] = __builtin_amdgcn_mfma_f32_16x16x32_bf16(
                    a[mi][1], b[ni][1], acc[mi][ni], 0, 0, 0);
            }
    }

    const int tid = n0 >> 10;   // 0..3 = q1,q2,k1,k2 ; 4 = v (block-uniform)
    const float* bias = (tid == 0) ? bq1 : (tid == 1) ? bq2 :
                        (tid == 2) ? bk1 : (tid == 3) ? bk2 : bv;
    const float scl = (tid <= 1) ? QSCALE_LOG2E : 1.0f;
    const size_t nQKV = (size_t)NH * S_LEN * DHD;

    #pragma unroll
    for (int ni = 0; ni < 4; ++ni) {
        const int n = n0 + wc + ni * 16 + lane15;
        const int h = (n >> 6) & 15, d = n & 63;
        const float bb = bias[n & 1023];
        #pragma unroll
        for (int mi = 0; mi < 4; ++mi) {
            const int m = m0 + wr + mi * 16 + quad * 4;
            if (tid < 4) {
                u16* o = qk + tid * nQKV + ((size_t)h * S_LEN + m) * DHD + d;
                #pragma unroll
                for (int r = 0; r < 4; ++r)
                    o[r * DHD] = f2bf((acc[mi][ni][r] + bb) * scl);
            } else {
                U16x4 pk;
                pk.x = f2bf(acc[mi][ni][0] + bb);
                pk.y = f2bf(acc[mi][ni][1] + bb);
                pk.z = f2bf(acc[mi][ni][2] + bb);
                pk.w = f2bf(acc[mi][ni][3] + bb);
                *(U16x4*)(vt + ((size_t)h * DHD + d) * S_LEN + m) = pk;
            }
        }
    }
}

// ---------------------------------------------------------------------------
// MFMA flash attention, causal. p = 2^s (scale*log2e folded into q), no
// running max (|s| << 88). P stored to per-wave LDS via truncating d16_hi
// stores (zero VALU). Double-buffered K/V, one barrier per k-tile.
// grid (32, NH, 2): one 64-row q-tile per block, qt = 31-bx (longest first).
// Output o in bf16.
// ---------------------------------------------------------------------------
__global__ __launch_bounds__(256) void attn_mfma_kernel(
    const u16* __restrict__ qbase, const u16* __restrict__ kbase,
    const u16* __restrict__ vtb, u16* __restrict__ obase)
{
    __shared__ u16 Qs[64 * 64];
    __shared__ u16 Ks[2][64 * 64], Vs[2][64 * 64];
    __shared__ u16 Ps[4][16 * 64];
    const int z = blockIdx.z, h = blockIdx.y;
    const int qt = 31 - blockIdx.x;             // longest blocks dispatch first
    const int q0 = qt * 64;
    const size_t per = (size_t)NH * S_LEN * DHD;
    const u16* qg = qbase + z * per + (size_t)h * S_LEN * DHD;
    const u16* kg = kbase + z * per + (size_t)h * S_LEN * DHD;
    const u16* vg = vtb + (size_t)h * DHD * S_LEN;          // vt[h][d][s]
    u16* og = obase + z * per + (size_t)h * S_LEN * DHD;
    const int t = threadIdx.x, w = t >> 6, l = t & 63;
    const int lane15 = l & 15, quad = l >> 4;
    u16* Pw = Ps[w];

    // stage Q and first K/V tile (published by the kt=0 barrier)
    stage8(qg + (size_t)q0 * DHD, DHD, Qs, w * 16, l);
    stage8(qg + (size_t)q0 * DHD, DHD, Qs, w * 16 + 8, l);
    stage8(kg, DHD, Ks[0], w * 16, l);
    stage8(kg, DHD, Ks[0], w * 16 + 8, l);
    stage8(vg, S_LEN, Vs[0], w * 16, l);
    stage8(vg, S_LEN, Vs[0], w * 16 + 8, l);

    f32x4 O[4];
    float lsum[4];
    #pragma unroll
    for (int i = 0; i < 4; ++i) { O[i] = fzero(); lsum[i] = 0.f; }
    bf16x8 qa0, qa1;

    for (int kt = 0; kt <= qt; ++kt) {
        const int cur = kt & 1;
        __syncthreads();   // drains vmcnt: buf[cur] (and Qs at kt=0) ready
        if (kt < qt) {     // prefetch next tile into the other buffer
            const int t1 = (kt + 1) * 64;
            stage8(kg + (size_t)t1 * DHD, DHD, Ks[cur ^ 1], w * 16, l);
            stage8(kg + (size_t)t1 * DHD, DHD, Ks[cur ^ 1], w * 16 + 8, l);
            stage8(vg + t1, S_LEN, Vs[cur ^ 1], w * 16, l);
            stage8(vg + t1, S_LEN, Vs[cur ^ 1], w * 16 + 8, l);
        }
        if (kt == 0) {
            qa0 = ldsfrag(Qs, w * 16 + lane15, quad);
            qa1 = ldsfrag(Qs, w * 16 + lane15, 4 + quad);
        }

        // S = Q K^T (pre-scaled by 1/8*log2e via q)
        f32x4 sc[4];
        #pragma unroll
        for (int nt = 0; nt < 4; ++nt) {
            sc[nt] = fzero();
            bf16x8 b0 = ldsfrag(Ks[cur], nt * 16 + lane15, quad);
            bf16x8 b1 = ldsfrag(Ks[cur], nt * 16 + lane15, 4 + quad);
            sc[nt] = __builtin_amdgcn_mfma_f32_16x16x32_bf16(qa0, b0, sc[nt], 0, 0, 0);
            sc[nt] = __builtin_amdgcn_mfma_f32_16x16x32_bf16(qa1, b1, sc[nt], 0, 0, 0);
        }

        const bool diag = (kt == qt);
        #pragma unroll
        for (int r = 0; r < 4; ++r) {
            const int lr = quad * 4 + r;
            const int qrl = w * 16 + lr;   // local q row (diag tile col space)
            float p0 = __builtin_amdgcn_exp2f(sc[0][r]);
            float p1 = __builtin_amdgcn_exp2f(sc[1][r]);
            float p2 = __builtin_amdgcn_exp2f(sc[2][r]);
            float p3 = __builtin_amdgcn_exp2f(sc[3][r]);
            if (diag) {
                if (lane15      > qrl) p0 = 0.f;
                if (16 + lane15 > qrl) p1 = 0.f;
                if (32 + lane15 > qrl) p2 = 0.f;
                if (48 + lane15 > qrl) p3 = 0.f;
            }
            lsum[r] += (p0 + p1) + (p2 + p3);
            const int cb = (lane15 & 7) * 2;
            const int ch = lane15 >> 3;
            char* pb = (char*)Pw + lr * 128;
            // truncating bf16 stores: ds_write_b16_d16_hi, no VALU rounding
            *(u16*)(pb + (((0 + ch) ^ (lr & 7)) << 4) + cb) = f2bf_trunc(p0);
            *(u16*)(pb + (((2 + ch) ^ (lr & 7)) << 4) + cb) = f2bf_trunc(p1);
            *(u16*)(pb + (((4 + ch) ^ (lr & 7)) << 4) + cb) = f2bf_trunc(p2);
            *(u16*)(pb + (((6 + ch) ^ (lr & 7)) << 4) + cb) = f2bf_trunc(p3);
        }

        // O += P V  (Ps is per-wave: same-wave LDS order, no barrier)
        bf16x8 pa0 = ldsfrag(Pw, lane15, quad);
        bf16x8 pa1 = ldsfrag(Pw, lane15, 4 + quad);
        #pragma unroll
        for (int nt = 0; nt < 4; ++nt) {
            bf16x8 v0 = ldsfrag(Vs[cur], nt * 16 + lane15, quad);
            bf16x8 v1 = ldsfrag(Vs[cur], nt * 16 + lane15, 4 + quad);
            O[nt] = __builtin_amdgcn_mfma_f32_16x16x32_bf16(pa0, v0, O[nt], 0, 0, 0);
            O[nt] = __builtin_amdgcn_mfma_f32_16x16x32_bf16(pa1, v1, O[nt], 0, 0, 0);
        }
    }

    float inv[4];
    #pragma unroll
    for (int r = 0; r < 4; ++r) {
        float rs = lsum[r];
        rs += __shfl_xor(rs, 1);
        rs += __shfl_xor(rs, 2);
        rs += __shfl_xor(rs, 4);
        rs += __shfl_xor(rs, 8);
        inv[r] = 1.f / rs;
    }
    u16* orow = og + (size_t)(q0 + w * 16 + quad * 4) * DHD;
    #pragma unroll
    for (int nt = 0; nt < 4; ++nt) {
        const int d = nt * 16 + lane15;
        #pragma unroll
        for (int r = 0; r < 4; ++r)
            orow[r * DHD + d] = f2bf(O[nt][r] * inv[r]);
    }
}

// ---------------------------------------------------------------------------
// GroupNorm stats over (o1 - lam*o2), per head, bf16 inputs. grid (NH, 8)
// ---------------------------------------------------------------------------
__global__ __launch_bounds__(256) void gn_stats_kernel(
    const u16* __restrict__ o1, const u16* __restrict__ o2,
    const float* __restrict__ lam, float* __restrict__ part)
{
    const int h = blockIdx.x, p = blockIdx.y;
    const float vlam = lam[h];
    const int chunk = S_LEN * DHD / 8;            // 16384 elements
    const size_t base = (size_t)h * (S_LEN * DHD) + (size_t)p * chunk;
    const uint4* a = (const uint4*)(o1 + base);   // 8 bf16 per uint4
    const uint4* b = (const uint4*)(o2 + base);
    float s = 0.f, ss = 0.f;
    for (int i = threadIdx.x; i < chunk / 8; i += 256) {
        uint4 av = a[i], bv = b[i];
        const unsigned aw[4] = {av.x, av.y, av.z, av.w};
        const unsigned bw[4] = {bv.x, bv.y, bv.z, bv.w};
        #pragma unroll
        for (int j = 0; j < 4; ++j) {
            union { unsigned u; float f; } lo_a, hi_a, lo_b, hi_b;
            lo_a.u = aw[j] << 16; hi_a.u = aw[j] & 0xffff0000u;
            lo_b.u = bw[j] << 16; hi_b.u = bw[j] & 0xffff0000u;
            float v0 = lo_a.f - vlam * lo_b.f;
            float v1 = hi_a.f - vlam * hi_b.f;
            s += v0 + v1;
            ss += v0 * v0 + v1 * v1;
        }
    }
    #pragma unroll
    for (int d = 1; d < 64; d <<= 1) { s += __shfl_xor(s, d); ss += __shfl_xor(ss, d); }
    __shared__ float red[8];
    const int w = threadIdx.x >> 6;
    if ((threadIdx.x & 63) == 0) { red[2 * w] = s; red[2 * w + 1] = ss; }
    __syncthreads();
    if (threadIdx.x == 0) {
        float S  = (red[0] + red[2]) + (red[4] + red[6]);
        float SS = (red[1] + red[3]) + (red[5] + red[7]);
        part[(blockIdx.x * 8 + p) * 2]     = S;
        part[(blockIdx.x * 8 + p) * 2 + 1] = SS;
    }
}

// Combine + normalize + affine -> xn bf16 [s][d]; finalizes stats inline.
// 4 elements per thread. grid nQKV/1024.
__global__ __launch_bounds__(256) void gn_apply_kernel(
    const u16* __restrict__ o1, const u16* __restrict__ o2,
    const float* __restrict__ lam, const float* __restrict__ part,
    const float* __restrict__ gw, const float* __restrict__ gb,
    u16* __restrict__ xnb)
{
    const int i4 = (blockIdx.x * 256 + threadIdx.x) * 4;
    const int dh = i4 & 63;
    const int s  = (i4 >> 6) & (S_LEN - 1);
    const int h  = i4 >> 17;
    const int d  = h * DHD + dh;
    float sum = 0.f, ssum = 0.f;
    #pragma unroll
    for (int p = 0; p < 8; ++p) {
        sum  += part[(h * 8 + p) * 2];
        ssum += part[(h * 8 + p) * 2 + 1];
    }
    const float n = (float)(S_LEN * DHD);
    const float mu = sum / n;
    const float rstd = rsqrtf(ssum / n - mu * mu + GN_EPS);
    const float vlam = lam[h];
    U16x4 a = *(const U16x4*)(o1 + i4);
    U16x4 b = *(const U16x4*)(o2 + i4);
    float4 g4 = *(const float4*)(gw + d);
    float4 b4 = *(const float4*)(gb + d);
    U16x4 o;
    o.x = f2bf((bf2f(a.x) - vlam * bf2f(b.x) - mu) * rstd * g4.x + b4.x);
    o.y = f2bf((bf2f(a.y) - vlam * bf2f(b.y) - mu) * rstd * g4.y + b4.y);
    o.z = f2bf((bf2f(a.z) - vlam * bf2f(b.z) - mu) * rstd * g4.z + b4.z);
    o.w = f2bf((bf2f(a.w) - vlam * bf2f(b.w) - mu) * rstd * g4.w + b4.w);
    *(U16x4*)(xnb + (size_t)s * DMODEL + d) = o;
}

// ---------------------------------------------------------------------------
// Output GEMM 64x64 tile: out[s][e] = xn[s][:] . Wo[e][:] + bo[e]
// grid (32, 16)
// ---------------------------------------------------------------------------
__global__ __launch_bounds__(256) void out_mfma_kernel(
    const u16* __restrict__ xnb, const u16* __restrict__ wob,
    const float* __restrict__ bo, float* __restrict__ out)
{
    __shared__ u16 As[64 * 64], Bs[64 * 64];
    const int m0 = blockIdx.x * 64, n0 = blockIdx.y * 64;
    const int t = threadIdx.x, w = t >> 6, l = t & 63;
    const int lane15 = l & 15, quad = l >> 4;
    f32x4 acc[4];
    #pragma unroll
    for (int nt = 0; nt < 4; ++nt) acc[nt] = fzero();

    const u16* Ag = xnb + (size_t)m0 * DMODEL;
    const u16* Bg = wob + (size_t)n0 * DMODEL;
    for (int k0 = 0; k0 < DMODEL; k0 += 64) {
        __syncthreads();
        stage8(Ag + k0, DMODEL, As, w * 16, l);
        stage8(Ag + k0, DMODEL, As, w * 16 + 8, l);
        stage8(Bg + k0, DMODEL, Bs, w * 16, l);
        stage8(Bg + k0, DMODEL, Bs, w * 16 + 8, l);
        __syncthreads();
        bf16x8 a0 = ldsfrag(As, w * 16 + lane15, quad);
        bf16x8 a1 = ldsfrag(As, w * 16 + lane15, 4 + quad);
        #pragma unroll
        for (int nt = 0; nt < 4; ++nt) {
            bf16x8 b0 = ldsfrag(Bs, nt * 16 + lane15, quad);
            bf16x8 b1 = ldsfrag(Bs, nt * 16 + lane15, 4 + quad);
            acc[nt] = __builtin_amdgcn_mfma_f32_16x16x32_bf16(a0, b0, acc[nt], 0, 0, 0);
            acc[nt] = __builtin_amdgcn_mfma_f32_16x16x32_bf16(a1, b1, acc[nt], 0, 0, 0);
        }
    }
    #pragma unroll
    for (int nt = 0; nt < 4; ++nt) {
        const int n = n0 + nt * 16 + lane15;
        const float bb = bo[n];
        #pragma unroll
        for (int r = 0; r < 4; ++r)
            out[(size_t)(m0 + w * 16 + quad * 4 + r) * E_DIM + n] = acc[nt][r] + bb;
    }
}

// ---------------------------------------------------------------------------
extern "C" void kernel_launch(void* const* d_in, const int* in_sizes, int n_in,
                              void* d_out, int out_size, void* d_ws, size_t ws_size,
                              hipStream_t stream)
{
    const float* x   = (const float*)d_in[0];
    const float* Wq1 = (const float*)d_in[2];
    const float* bq1 = (const float*)d_in[3];
    const float* Wq2 = (const float*)d_in[4];
    const float* bq2 = (const float*)d_in[5];
    const float* Wk1 = (const float*)d_in[6];
    const float* bk1 = (const float*)d_in[7];
    const float* Wk2 = (const float*)d_in[8];
    const float* bk2 = (const float*)d_in[9];
    const float* Wv  = (const float*)d_in[10];
    const float* bv  = (const float*)d_in[11];
    const float* lam = (const float*)d_in[12];
    const float* gw  = (const float*)d_in[13];
    const float* gb  = (const float*)d_in[14];
    const float* Wo  = (const float*)d_in[15];
    const float* bo  = (const float*)d_in[16];
    float* out = (float*)d_out;

    char* p = (char*)d_ws;
    auto take = [&](size_t bytes) { char* r = p; p += (bytes + 255) & ~(size_t)255; return r; };
    const size_t nQKV = (size_t)NH * S_LEN * DHD;     // 2M elements

    u16* xb   = (u16*)take(2 * (size_t)S_LEN * E_DIM);
    u16* wall = (u16*)take(2 * (size_t)5 * NH * DHD * E_DIM);   // [5120][1024]
    u16* wob  = (u16*)take(2 * (size_t)DMODEL * E_DIM);
    u16* qk   = (u16*)take(2 * 4 * nQKV);             // q1,q2,k1,k2 contiguous
    u16* vtb  = (u16*)take(2 * nQKV);
    u16* o1   = (u16*)take(2 * 2 * nQKV);             // o1,o2 contiguous, bf16
    u16* xnb  = (u16*)take(2 * (size_t)S_LEN * DMODEL);
    float* part = (float*)take(4 * 256);

    f2b_kernel<<<dim3(2048, 1, 7), 256, 0, stream>>>(
        x, Wq1, Wq2, Wk1, Wk2, Wv, Wo, xb, wall, wob);

    proj_mfma_kernel<<<dim3(16, 40), 256, 0, stream>>>(
        xb, wall, bq1, bq2, bk1, bk2, bv, qk, vtb);

    attn_mfma_kernel<<<dim3(32, NH, 2), 256, 0, stream>>>(
        qk, qk + 2 * nQKV, vtb, o1);

    gn_stats_kernel<<<dim3(NH, 8), 256, 0, stream>>>(o1, o1 + nQKV, lam, part);
    gn_apply_kernel<<<dim3((int)(nQKV / 1024)), 256, 0, stream>>>(
        o1, o1 + nQKV, lam, part, gw, gb, xnb);

    out_mfma_kernel<<<dim3(32, 16), 256, 0, stream>>>(xnb, wob, bo, out);
}

// Round 5
// 219.528 us; speedup vs baseline: 1.1375x; 1.1375x over previous
//
#include <hip/hip_runtime.h>

#define S_LEN 2048
#define E_DIM 1024
#define NH 16
#define DHD 64
#define DMODEL 1024

typedef unsigned short u16;
typedef __attribute__((ext_vector_type(8))) short bf16x8;   // 8 bf16 = 4 VGPRs
typedef __attribute__((ext_vector_type(4))) float f32x4;

static constexpr float GN_EPS = 1e-5f;
// 1/sqrt(64) * log2(e): scores pre-scaled so softmax uses raw v_exp_f32 (2^x)
static constexpr float QSCALE_LOG2E = 0.125f * 1.44269504088896340736f;

struct alignas(8) U16x4 { u16 x, y, z, w; };

__device__ __forceinline__ u16 f2bf(float f) {            // RNE
    union { float f; unsigned u; } v; v.f = f;
    unsigned r = v.u + 0x7fffu + ((v.u >> 16) & 1u);
    return (u16)(r >> 16);
}
__device__ __forceinline__ u16 f2bf_trunc(float f) {      // truncate: free via d16_hi store
    union { float f; unsigned u; } v; v.f = f;
    return (u16)(v.u >> 16);
}
__device__ __forceinline__ float bf2f(u16 u) {
    union { unsigned u; float f; } v; v.u = ((unsigned)u) << 16; return v.f;
}

__device__ __forceinline__ f32x4 fzero() { f32x4 z = {0.f, 0.f, 0.f, 0.f}; return z; }

// ---------------------------------------------------------------------------
// async 16B/lane global->LDS. LDS dest = wave-uniform base + lane*16.
// ---------------------------------------------------------------------------
__device__ __forceinline__ void async16(const u16* g, u16* l) {
    __builtin_amdgcn_global_load_lds(
        (const __attribute__((address_space(1))) unsigned int*)g,
        (__attribute__((address_space(3))) unsigned int*)l, 16, 0, 0);
}

// Stage 8 rows (r0..r0+7, r0 % 8 == 0) of a 64-col bf16 tile into XOR-swizzled
// LDS. Logical (r,c) lives at byte r*128 + (((c>>3) ^ (r&7))*16) + (c&7)*2.
// ONE vm-op per wave per call.
__device__ __forceinline__ void stage8(const u16* gbase, int gstride, u16* lds,
                                       int r0, int l) {
    const int cg = (l & 7) ^ (l >> 3);
    async16(gbase + (size_t)(r0 + (l >> 3)) * gstride + cg * 8, lds + r0 * 64);
}

__device__ __forceinline__ bf16x8 ldsfrag(const u16* lds, int r, int chunk) {
    return *(const bf16x8*)((const char*)lds + r * 128 + ((chunk ^ (r & 7)) << 4));
}

// ---------------------------------------------------------------------------
// fp32 -> bf16: x, 5 projection weights (into one concatenated [5120][1024]
// buffer), Wo. grid.z selects tensor.
// ---------------------------------------------------------------------------
__global__ __launch_bounds__(256) void f2b_kernel(
    const float* __restrict__ x,
    const float* __restrict__ w0, const float* __restrict__ w1,
    const float* __restrict__ w2, const float* __restrict__ w3,
    const float* __restrict__ w4, const float* __restrict__ wo,
    u16* __restrict__ xb, u16* __restrict__ wall, u16* __restrict__ dwo)
{
    const int z = blockIdx.z;
    const float* src; u16* dst; int n;
    const int nw = NH * DHD * E_DIM;
    switch (z) {
        case 0: src = x;  dst = xb;            n = S_LEN * E_DIM;  break;
        case 1: src = w0; dst = wall;          n = nw; break;
        case 2: src = w1; dst = wall + nw;     n = nw; break;
        case 3: src = w2; dst = wall + 2 * nw; n = nw; break;
        case 4: src = w3; dst = wall + 3 * nw; n = nw; break;
        case 5: src = w4; dst = wall + 4 * nw; n = nw; break;
        default: src = wo; dst = dwo;          n = DMODEL * E_DIM; break;
    }
    int i = blockIdx.x * 256 + threadIdx.x;
    if (i * 4 < n) {
        float4 v = ((const float4*)src)[i];
        U16x4 o;
        o.x = f2bf(v.x); o.y = f2bf(v.y); o.z = f2bf(v.z); o.w = f2bf(v.w);
        ((U16x4*)dst)[i] = o;
    }
}

// ---------------------------------------------------------------------------
// Fused projection GEMM: [2048 x 1024] x [5120 x 1024]^T, 128x128 tile.
// n -> {tensor t, head h, dim d}. q1/q2 pre-scaled by QSCALE_LOG2E;
// v written transposed vt[h][d][s].  grid (16, 40), 4 waves, 4x4 accs each.
// ---------------------------------------------------------------------------
__global__ __launch_bounds__(256) void proj_mfma_kernel(
    const u16* __restrict__ xb, const u16* __restrict__ wall,
    const float* __restrict__ bq1, const float* __restrict__ bq2,
    const float* __restrict__ bk1, const float* __restrict__ bk2,
    const float* __restrict__ bv,
    u16* __restrict__ qk, u16* __restrict__ vt)
{
    __shared__ u16 As[128 * 64], Bs[128 * 64];
    const int m0 = blockIdx.x * 128, n0 = blockIdx.y * 128;
    const int t = threadIdx.x, w = t >> 6, l = t & 63;
    const int lane15 = l & 15, quad = l >> 4;
    const int wr = (w >> 1) * 64, wc = (w & 1) * 64;

    f32x4 acc[4][4];
    #pragma unroll
    for (int mi = 0; mi < 4; ++mi)
        #pragma unroll
        for (int ni = 0; ni < 4; ++ni) acc[mi][ni] = fzero();

    const u16* Ag = xb + (size_t)m0 * E_DIM;
    const u16* Bg = wall + (size_t)n0 * E_DIM;

    for (int k0 = 0; k0 < E_DIM; k0 += 64) {
        __syncthreads();
        #pragma unroll
        for (int i = 0; i < 4; ++i) stage8(Ag + k0, E_DIM, As, w * 32 + i * 8, l);
        #pragma unroll
        for (int i = 0; i < 4; ++i) stage8(Bg + k0, E_DIM, Bs, w * 32 + i * 8, l);
        __syncthreads();

        bf16x8 a[4][2], b[4][2];
        #pragma unroll
        for (int mi = 0; mi < 4; ++mi) {
            a[mi][0] = ldsfrag(As, wr + mi * 16 + lane15, quad);
            a[mi][1] = ldsfrag(As, wr + mi * 16 + lane15, 4 + quad);
        }
        #pragma unroll
        for (int ni = 0; ni < 4; ++ni) {
            b[ni][0] = ldsfrag(Bs, wc + ni * 16 + lane15, quad);
            b[ni][1] = ldsfrag(Bs, wc + ni * 16 + lane15, 4 + quad);
        }
        #pragma unroll
        for (int mi = 0; mi < 4; ++mi)
            #pragma unroll
            for (int ni = 0; ni < 4; ++ni) {
                acc[mi][ni] = __builtin_amdgcn_mfma_f32_16x16x32_bf16(
                    a[mi][0], b[ni][0], acc[mi][ni], 0, 0, 0);
                acc[mi][ni] = __builtin_amdgcn_mfma_f32_16x16x32_bf16(
                    a[mi][1], b[ni][1], acc[mi][ni], 0, 0, 0);
            }
    }

    const int tid = n0 >> 10;   // 0..3 = q1,q2,k1,k2 ; 4 = v (block-uniform)
    const float* bias = (tid == 0) ? bq1 : (tid == 1) ? bq2 :
                        (tid == 2) ? bk1 : (tid == 3) ? bk2 : bv;
    const float scl = (tid <= 1) ? QSCALE_LOG2E : 1.0f;
    const size_t nQKV = (size_t)NH * S_LEN * DHD;

    #pragma unroll
    for (int ni = 0; ni < 4; ++ni) {
        const int n = n0 + wc + ni * 16 + lane15;
        const int h = (n >> 6) & 15, d = n & 63;
        const float bb = bias[n & 1023];
        #pragma unroll
        for (int mi = 0; mi < 4; ++mi) {
            const int m = m0 + wr + mi * 16 + quad * 4;
            if (tid < 4) {
                u16* o = qk + tid * nQKV + ((size_t)h * S_LEN + m) * DHD + d;
                #pragma unroll
                for (int r = 0; r < 4; ++r)
                    o[r * DHD] = f2bf((acc[mi][ni][r] + bb) * scl);
            } else {
                U16x4 pk;
                pk.x = f2bf(acc[mi][ni][0] + bb);
                pk.y = f2bf(acc[mi][ni][1] + bb);
                pk.z = f2bf(acc[mi][ni][2] + bb);
                pk.w = f2bf(acc[mi][ni][3] + bb);
                *(U16x4*)(vt + ((size_t)h * DHD + d) * S_LEN + m) = pk;
            }
        }
    }
}

// ---------------------------------------------------------------------------
// MFMA flash attention, causal. p = 2^s (scale*log2e folded into q), no
// running max. P via truncating per-wave LDS stores. Q fragments live in
// registers (plain global loads). K/V TRIPLE-buffered with prefetch 2 tiles
// ahead; per-tile sync is raw s_barrier preceded by s_waitcnt vmcnt(4):
// the newest 4 vm-ops (tile kt+2 prefetch) stay in flight across the
// barrier, so the consumed buffer (staged 2 tiles ago) never stalls.
// grid (16, NH, 2): block bb does q-tiles bb and 31-bb (uniform 33 k-tiles).
// ---------------------------------------------------------------------------
__global__ __launch_bounds__(256) void attn_mfma_kernel(
    const u16* __restrict__ qbase, const u16* __restrict__ kbase,
    const u16* __restrict__ vtb, u16* __restrict__ obase)
{
    __shared__ u16 Ks[3][64 * 64], Vs[3][64 * 64];   // 48 KB
    __shared__ u16 Ps[4][16 * 64];                   //  8 KB
    const int z = blockIdx.z, h = blockIdx.y, bb = blockIdx.x;
    const size_t per = (size_t)NH * S_LEN * DHD;
    const u16* qg = qbase + z * per + (size_t)h * S_LEN * DHD;
    const u16* kg = kbase + z * per + (size_t)h * S_LEN * DHD;
    const u16* vg = vtb + (size_t)h * DHD * S_LEN;          // vt[h][d][s]
    u16* og = obase + z * per + (size_t)h * S_LEN * DHD;
    const int t = threadIdx.x, w = t >> 6, l = t & 63;
    const int lane15 = l & 15, quad = l >> 4;
    u16* Pw = Ps[w];

    for (int half = 0; half < 2; ++half) {
        const int qt = half ? (31 - bb) : bb;
        const int q0 = qt * 64;

        // Q fragments from global: A[m=lane15][k=quad*8+j], rows contiguous.
        const u16* qrow = qg + (size_t)(q0 + w * 16 + lane15) * DHD + quad * 8;
        bf16x8 qa0 = *(const bf16x8*)(qrow);
        bf16x8 qa1 = *(const bf16x8*)(qrow + 32);

        // prologue: stage k-tiles 0 and 1 (4 vm-ops per wave per tile)
        stage8(kg, DHD, Ks[0], w * 16, l);
        stage8(kg, DHD, Ks[0], w * 16 + 8, l);
        stage8(vg, S_LEN, Vs[0], w * 16, l);
        stage8(vg, S_LEN, Vs[0], w * 16 + 8, l);
        if (qt >= 1) {
            stage8(kg + (size_t)64 * DHD, DHD, Ks[1], w * 16, l);
            stage8(kg + (size_t)64 * DHD, DHD, Ks[1], w * 16 + 8, l);
            stage8(vg + 64, S_LEN, Vs[1], w * 16, l);
            stage8(vg + 64, S_LEN, Vs[1], w * 16 + 8, l);
        }

        f32x4 O[4];
        float lsum[4];
        #pragma unroll
        for (int i = 0; i < 4; ++i) { O[i] = fzero(); lsum[i] = 0.f; }

        int cur = 0, pre = 2;
        for (int kt = 0; kt <= qt; ++kt) {
            // invariant at entry: outstanding vm = stage(kt)[oldest 4]
            //                     (+ stage(kt+1)[newest 4] iff kt < qt)
            if (kt < qt) asm volatile("s_waitcnt vmcnt(4)" ::: "memory");
            else         asm volatile("s_waitcnt vmcnt(0)" ::: "memory");
            asm volatile("s_barrier" ::: "memory");
            if (kt + 2 <= qt) {   // prefetch 2 ahead into the retired buffer
                const int t2 = (kt + 2) * 64;
                stage8(kg + (size_t)t2 * DHD, DHD, Ks[pre], w * 16, l);
                stage8(kg + (size_t)t2 * DHD, DHD, Ks[pre], w * 16 + 8, l);
                stage8(vg + t2, S_LEN, Vs[pre], w * 16, l);
                stage8(vg + t2, S_LEN, Vs[pre], w * 16 + 8, l);
            }
            const u16* Kc = Ks[cur];
            const u16* Vc = Vs[cur];

            // S = Q K^T (pre-scaled by 1/8*log2e via q)
            f32x4 sc[4];
            #pragma unroll
            for (int nt = 0; nt < 4; ++nt) {
                sc[nt] = fzero();
                bf16x8 b0 = ldsfrag(Kc, nt * 16 + lane15, quad);
                bf16x8 b1 = ldsfrag(Kc, nt * 16 + lane15, 4 + quad);
                sc[nt] = __builtin_amdgcn_mfma_f32_16x16x32_bf16(qa0, b0, sc[nt], 0, 0, 0);
                sc[nt] = __builtin_amdgcn_mfma_f32_16x16x32_bf16(qa1, b1, sc[nt], 0, 0, 0);
            }

            const bool diag = (kt == qt);
            #pragma unroll
            for (int r = 0; r < 4; ++r) {
                const int lr = quad * 4 + r;
                const int qrl = w * 16 + lr;   // local q row (diag tile col space)
                float p0 = __builtin_amdgcn_exp2f(sc[0][r]);
                float p1 = __builtin_amdgcn_exp2f(sc[1][r]);
                float p2 = __builtin_amdgcn_exp2f(sc[2][r]);
                float p3 = __builtin_amdgcn_exp2f(sc[3][r]);
                if (diag) {
                    if (lane15      > qrl) p0 = 0.f;
                    if (16 + lane15 > qrl) p1 = 0.f;
                    if (32 + lane15 > qrl) p2 = 0.f;
                    if (48 + lane15 > qrl) p3 = 0.f;
                }
                lsum[r] += (p0 + p1) + (p2 + p3);
                const int cb = (lane15 & 7) * 2;
                const int ch = lane15 >> 3;
                char* pb = (char*)Pw + lr * 128;
                *(u16*)(pb + (((0 + ch) ^ (lr & 7)) << 4) + cb) = f2bf_trunc(p0);
                *(u16*)(pb + (((2 + ch) ^ (lr & 7)) << 4) + cb) = f2bf_trunc(p1);
                *(u16*)(pb + (((4 + ch) ^ (lr & 7)) << 4) + cb) = f2bf_trunc(p2);
                *(u16*)(pb + (((6 + ch) ^ (lr & 7)) << 4) + cb) = f2bf_trunc(p3);
            }

            // O += P V  (Ps per-wave: same-wave LDS order, compiler lgkmcnt)
            bf16x8 pa0 = ldsfrag(Pw, lane15, quad);
            bf16x8 pa1 = ldsfrag(Pw, lane15, 4 + quad);
            #pragma unroll
            for (int nt = 0; nt < 4; ++nt) {
                bf16x8 v0 = ldsfrag(Vc, nt * 16 + lane15, quad);
                bf16x8 v1 = ldsfrag(Vc, nt * 16 + lane15, 4 + quad);
                O[nt] = __builtin_amdgcn_mfma_f32_16x16x32_bf16(pa0, v0, O[nt], 0, 0, 0);
                O[nt] = __builtin_amdgcn_mfma_f32_16x16x32_bf16(pa1, v1, O[nt], 0, 0, 0);
            }
            cur = (cur == 2) ? 0 : cur + 1;
            pre = (pre == 2) ? 0 : pre + 1;
        }

        float inv[4];
        #pragma unroll
        for (int r = 0; r < 4; ++r) {
            float rs = lsum[r];
            rs += __shfl_xor(rs, 1);
            rs += __shfl_xor(rs, 2);
            rs += __shfl_xor(rs, 4);
            rs += __shfl_xor(rs, 8);
            inv[r] = 1.f / rs;
        }
        u16* orow = og + (size_t)(q0 + w * 16 + quad * 4) * DHD;
        #pragma unroll
        for (int nt = 0; nt < 4; ++nt) {
            const int d = nt * 16 + lane15;
            #pragma unroll
            for (int r = 0; r < 4; ++r)
                orow[r * DHD + d] = f2bf(O[nt][r] * inv[r]);
        }
        __syncthreads();   // full drain before next half restages buffers
    }
}

// ---------------------------------------------------------------------------
// GroupNorm stats over (o1 - lam*o2), per head, bf16 inputs. grid (NH, 8)
// ---------------------------------------------------------------------------
__global__ __launch_bounds__(256) void gn_stats_kernel(
    const u16* __restrict__ o1, const u16* __restrict__ o2,
    const float* __restrict__ lam, float* __restrict__ part)
{
    const int h = blockIdx.x, p = blockIdx.y;
    const float vlam = lam[h];
    const int chunk = S_LEN * DHD / 8;            // 16384 elements
    const size_t base = (size_t)h * (S_LEN * DHD) + (size_t)p * chunk;
    const uint4* a = (const uint4*)(o1 + base);   // 8 bf16 per uint4
    const uint4* b = (const uint4*)(o2 + base);
    float s = 0.f, ss = 0.f;
    for (int i = threadIdx.x; i < chunk / 8; i += 256) {
        uint4 av = a[i], bv = b[i];
        const unsigned aw[4] = {av.x, av.y, av.z, av.w};
        const unsigned bw[4] = {bv.x, bv.y, bv.z, bv.w};
        #pragma unroll
        for (int j = 0; j < 4; ++j) {
            union { unsigned u; float f; } lo_a, hi_a, lo_b, hi_b;
            lo_a.u = aw[j] << 16; hi_a.u = aw[j] & 0xffff0000u;
            lo_b.u = bw[j] << 16; hi_b.u = bw[j] & 0xffff0000u;
            float v0 = lo_a.f - vlam * lo_b.f;
            float v1 = hi_a.f - vlam * hi_b.f;
            s += v0 + v1;
            ss += v0 * v0 + v1 * v1;
        }
    }
    #pragma unroll
    for (int d = 1; d < 64; d <<= 1) { s += __shfl_xor(s, d); ss += __shfl_xor(ss, d); }
    __shared__ float red[8];
    const int w = threadIdx.x >> 6;
    if ((threadIdx.x & 63) == 0) { red[2 * w] = s; red[2 * w + 1] = ss; }
    __syncthreads();
    if (threadIdx.x == 0) {
        float S  = (red[0] + red[2]) + (red[4] + red[6]);
        float SS = (red[1] + red[3]) + (red[5] + red[7]);
        part[(blockIdx.x * 8 + p) * 2]     = S;
        part[(blockIdx.x * 8 + p) * 2 + 1] = SS;
    }
}

// Combine + normalize + affine -> xn bf16 [s][d]; finalizes stats inline.
// 4 elements per thread. grid nQKV/1024.
__global__ __launch_bounds__(256) void gn_apply_kernel(
    const u16* __restrict__ o1, const u16* __restrict__ o2,
    const float* __restrict__ lam, const float* __restrict__ part,
    const float* __restrict__ gw, const float* __restrict__ gb,
    u16* __restrict__ xnb)
{
    const int i4 = (blockIdx.x * 256 + threadIdx.x) * 4;
    const int dh = i4 & 63;
    const int s  = (i4 >> 6) & (S_LEN - 1);
    const int h  = i4 >> 17;
    const int d  = h * DHD + dh;
    float sum = 0.f, ssum = 0.f;
    #pragma unroll
    for (int p = 0; p < 8; ++p) {
        sum  += part[(h * 8 + p) * 2];
        ssum += part[(h * 8 + p) * 2 + 1];
    }
    const float n = (float)(S_LEN * DHD);
    const float mu = sum / n;
    const float rstd = rsqrtf(ssum / n - mu * mu + GN_EPS);
    const float vlam = lam[h];
    U16x4 a = *(const U16x4*)(o1 + i4);
    U16x4 b = *(const U16x4*)(o2 + i4);
    float4 g4 = *(const float4*)(gw + d);
    float4 b4 = *(const float4*)(gb + d);
    U16x4 o;
    o.x = f2bf((bf2f(a.x) - vlam * bf2f(b.x) - mu) * rstd * g4.x + b4.x);
    o.y = f2bf((bf2f(a.y) - vlam * bf2f(b.y) - mu) * rstd * g4.y + b4.y);
    o.z = f2bf((bf2f(a.z) - vlam * bf2f(b.z) - mu) * rstd * g4.z + b4.z);
    o.w = f2bf((bf2f(a.w) - vlam * bf2f(b.w) - mu) * rstd * g4.w + b4.w);
    *(U16x4*)(xnb + (size_t)s * DMODEL + d) = o;
}

// ---------------------------------------------------------------------------
// Output GEMM 64x64 tile: out[s][e] = xn[s][:] . Wo[e][:] + bo[e]
// grid (32, 16)
// ---------------------------------------------------------------------------
__global__ __launch_bounds__(256) void out_mfma_kernel(
    const u16* __restrict__ xnb, const u16* __restrict__ wob,
    const float* __restrict__ bo, float* __restrict__ out)
{
    __shared__ u16 As[64 * 64], Bs[64 * 64];
    const int m0 = blockIdx.x * 64, n0 = blockIdx.y * 64;
    const int t = threadIdx.x, w = t >> 6, l = t & 63;
    const int lane15 = l & 15, quad = l >> 4;
    f32x4 acc[4];
    #pragma unroll
    for (int nt = 0; nt < 4; ++nt) acc[nt] = fzero();

    const u16* Ag = xnb + (size_t)m0 * DMODEL;
    const u16* Bg = wob + (size_t)n0 * DMODEL;
    for (int k0 = 0; k0 < DMODEL; k0 += 64) {
        __syncthreads();
        stage8(Ag + k0, DMODEL, As, w * 16, l);
        stage8(Ag + k0, DMODEL, As, w * 16 + 8, l);
        stage8(Bg + k0, DMODEL, Bs, w * 16, l);
        stage8(Bg + k0, DMODEL, Bs, w * 16 + 8, l);
        __syncthreads();
        bf16x8 a0 = ldsfrag(As, w * 16 + lane15, quad);
        bf16x8 a1 = ldsfrag(As, w * 16 + lane15, 4 + quad);
        #pragma unroll
        for (int nt = 0; nt < 4; ++nt) {
            bf16x8 b0 = ldsfrag(Bs, nt * 16 + lane15, quad);
            bf16x8 b1 = ldsfrag(Bs, nt * 16 + lane15, 4 + quad);
            acc[nt] = __builtin_amdgcn_mfma_f32_16x16x32_bf16(a0, b0, acc[nt], 0, 0, 0);
            acc[nt] = __builtin_amdgcn_mfma_f32_16x16x32_bf16(a1, b1, acc[nt], 0, 0, 0);
        }
    }
    #pragma unroll
    for (int nt = 0; nt < 4; ++nt) {
        const int n = n0 + nt * 16 + lane15;
        const float bb = bo[n];
        #pragma unroll
        for (int r = 0; r < 4; ++r)
            out[(size_t)(m0 + w * 16 + quad * 4 + r) * E_DIM + n] = acc[nt][r] + bb;
    }
}

// ---------------------------------------------------------------------------
extern "C" void kernel_launch(void* const* d_in, const int* in_sizes, int n_in,
                              void* d_out, int out_size, void* d_ws, size_t ws_size,
                              hipStream_t stream)
{
    const float* x   = (const float*)d_in[0];
    const float* Wq1 = (const float*)d_in[2];
    const float* bq1 = (const float*)d_in[3];
    const float* Wq2 = (const float*)d_in[4];
    const float* bq2 = (const float*)d_in[5];
    const float* Wk1 = (const float*)d_in[6];
    const float* bk1 = (const float*)d_in[7];
    const float* Wk2 = (const float*)d_in[8];
    const float* bk2 = (const float*)d_in[9];
    const float* Wv  = (const float*)d_in[10];
    const float* bv  = (const float*)d_in[11];
    const float* lam = (const float*)d_in[12];
    const float* gw  = (const float*)d_in[13];
    const float* gb  = (const float*)d_in[14];
    const float* Wo  = (const float*)d_in[15];
    const float* bo  = (const float*)d_in[16];
    float* out = (float*)d_out;

    char* p = (char*)d_ws;
    auto take = [&](size_t bytes) { char* r = p; p += (bytes + 255) & ~(size_t)255; return r; };
    const size_t nQKV = (size_t)NH * S_LEN * DHD;     // 2M elements

    u16* xb   = (u16*)take(2 * (size_t)S_LEN * E_DIM);
    u16* wall = (u16*)take(2 * (size_t)5 * NH * DHD * E_DIM);   // [5120][1024]
    u16* wob  = (u16*)take(2 * (size_t)DMODEL * E_DIM);
    u16* qk   = (u16*)take(2 * 4 * nQKV);             // q1,q2,k1,k2 contiguous
    u16* vtb  = (u16*)take(2 * nQKV);
    u16* o1   = (u16*)take(2 * 2 * nQKV);             // o1,o2 contiguous, bf16
    u16* xnb  = (u16*)take(2 * (size_t)S_LEN * DMODEL);
    float* part = (float*)take(4 * 256);

    f2b_kernel<<<dim3(2048, 1, 7), 256, 0, stream>>>(
        x, Wq1, Wq2, Wk1, Wk2, Wv, Wo, xb, wall, wob);

    proj_mfma_kernel<<<dim3(16, 40), 256, 0, stream>>>(
        xb, wall, bq1, bq2, bk1, bk2, bv, qk, vtb);

    attn_mfma_kernel<<<dim3(16, NH, 2), 256, 0, stream>>>(
        qk, qk + 2 * nQKV, vtb, o1);

    gn_stats_kernel<<<dim3(NH, 8), 256, 0, stream>>>(o1, o1 + nQKV, lam, part);
    gn_apply_kernel<<<dim3((int)(nQKV / 1024)), 256, 0, stream>>>(
        o1, o1 + nQKV, lam, part, gw, gb, xnb);

    out_mfma_kernel<<<dim3(32, 16), 256, 0, stream>>>(xnb, wob, bo, out);
}